// Round 20
// baseline (183.022 us; speedup 1.0000x reference)
//
#include <hip/hip_runtime.h>
#include <hip/hip_bf16.h>
#include <math.h>

#define HID 128
#define NH  8
#define SCHUNK 512  // elements per scan block
#define TPAD 136    // 128 + 8 shorts: 272B row stride (16B-aligned, bank-shifted)

typedef __attribute__((ext_vector_type(8))) short short8;
typedef __attribute__((ext_vector_type(4))) float f32x4;

static __device__ __forceinline__ float blo(unsigned int u) {
  union { unsigned int i; float f; } c; c.i = u << 16; return c.f;
}
static __device__ __forceinline__ float bhi(unsigned int u) {
  union { unsigned int i; float f; } c; c.i = u & 0xFFFF0000u; return c.f;
}
static __device__ __forceinline__ unsigned short f2bf(float f) {
  union { float f; unsigned int i; } c; c.f = f;
  unsigned int r = c.i + 0x7FFFu + ((c.i >> 16) & 1u);  // round-nearest-even
  return (unsigned short)(r >> 16);
}

// load 8 consecutive fp32 and convert to a bf16 MFMA fragment in-register
static __device__ __forceinline__ short8 ldconv8(const float* __restrict__ p) {
  float4 x = *(const float4*)p;
  float4 y = *(const float4*)(p + 4);
  short8 r;
  r[0] = (short)f2bf(x.x); r[1] = (short)f2bf(x.y);
  r[2] = (short)f2bf(x.z); r[3] = (short)f2bf(x.w);
  r[4] = (short)f2bf(y.x); r[5] = (short)f2bf(y.y);
  r[6] = (short)f2bf(y.z); r[7] = (short)f2bf(y.w);
  return r;
}

// ---------------- fused MFMA projection | histogram+rank (INTERLEAVED) -----
// Roles interleaved via Bresenham (co-resident on every CU): hist waves park
// on atomic returns (fabric-throughput floor, ~60us) while proj waves use the
// MFMA/LDS pipes. W is read fp32 and converted in-register (no convert pass).
__global__ __launch_bounds__(256) void proj_hist(
    const float* __restrict__ h,
    const float* __restrict__ Wq, const float* __restrict__ Wk,
    const float* __restrict__ Wv,
    const float* __restrict__ bq, const float* __restrict__ bk,
    const float* __restrict__ bv,
    unsigned short* __restrict__ qb, unsigned short* __restrict__ kvb,
    const int* __restrict__ src, int* __restrict__ deg, int* __restrict__ rank,
    int n, int bp, int nhist, int e) {
  __shared__ unsigned short tile[4][16][TPAD];  // per-wave 16x128 (+pad)

  const int P = 3 * bp;
  const int T = P + nhist;
  const long long a = (long long)blockIdx.x * P;
  const int d = (int)(a / T);
  const int c = (int)((a + P) / T);

  if (c == d) {
    // ---- histogram + rank role (hist_id = bx - c) ----
    int i = (blockIdx.x - c) * 256 + threadIdx.x;
    if (i < e) rank[i] = atomicAdd(&deg[src[i]], 1);
    return;
  }

  // ---- projection role (proj_id = d, each value in [0,P) exactly once) ----
  const int y = d / bp;
  const int bxx = d - y * bp;
  const float* W = (y == 0) ? Wq : (y == 1) ? Wk : Wv;
  const float* bias = (y == 0) ? bq : (y == 1) ? bk : bv;
  const float scale = (y == 0) ? 0.25f : 1.0f;  // q: DH^-0.5

  unsigned short* out;
  int ostride;
  if (y == 0)      { out = qb;        ostride = HID; }
  else if (y == 1) { out = kvb;       ostride = 2 * HID; }
  else             { out = kvb + HID; ostride = 2 * HID; }

  const int lane = threadIdx.x & 63;
  const int wave = threadIdx.x >> 6;
  const int n0 = bxx * 64 + wave * 16;

  int arow = n0 + (lane & 15);
  if (arow > n - 1) arow = n - 1;
  const int koff = (lane >> 4) * 8;

  const float* hr = h + (size_t)arow * HID + koff;
  short8 a0 = ldconv8(hr +  0);
  short8 a1 = ldconv8(hr + 32);
  short8 a2 = ldconv8(hr + 64);
  short8 a3 = ldconv8(hr + 96);

#pragma unroll
  for (int ct = 0; ct < 8; ++ct) {
    const int cc = ct * 16 + (lane & 15);
    const float* wr = W + (size_t)cc * HID + koff;
    short8 w0 = ldconv8(wr +  0);
    short8 w1 = ldconv8(wr + 32);
    short8 w2 = ldconv8(wr + 64);
    short8 w3 = ldconv8(wr + 96);
    f32x4 acc = {0.f, 0.f, 0.f, 0.f};
    acc = __builtin_amdgcn_mfma_f32_16x16x32_bf16(a0, w0, acc, 0, 0, 0);
    acc = __builtin_amdgcn_mfma_f32_16x16x32_bf16(a1, w1, acc, 0, 0, 0);
    acc = __builtin_amdgcn_mfma_f32_16x16x32_bf16(a2, w2, acc, 0, 0, 0);
    acc = __builtin_amdgcn_mfma_f32_16x16x32_bf16(a3, w3, acc, 0, 0, 0);

    const float bb = bias[cc];
    const int cp = (cc & 7) * 16 + (cc >> 3);  // head-major position within row
#pragma unroll
    for (int r = 0; r < 4; ++r) {
      int rl = (lane >> 4) * 4 + r;            // local row 0..15
      tile[wave][rl][cp] = f2bf((acc[r] + bb) * scale);
    }
  }

  // coalesced write-out: 16 rows x 256B, 16 lanes cover one row per pass
#pragma unroll
  for (int p = 0; p < 4; ++p) {
    int rl = p * 4 + (lane >> 4);
    int row = n0 + rl;
    if (row < n) {
      uint4 vv = *(const uint4*)&tile[wave][rl][(lane & 15) * 8];
      *(uint4*)(out + (size_t)row * ostride + (lane & 15) * 8) = vv;
    }
  }
}

__global__ __launch_bounds__(256) void reduce_blocks(
    const int* __restrict__ deg, int* __restrict__ partials, int n) {
  __shared__ int sm[256];
  int base = blockIdx.x * SCHUNK;
  int t = threadIdx.x;
  int i0 = base + t, i1 = base + t + 256;
  int s = ((i0 < n) ? deg[i0] : 0) + ((i1 < n) ? deg[i1] : 0);
  sm[t] = s;
  __syncthreads();
  for (int off = 128; off > 0; off >>= 1) {
    if (t < off) sm[t] += sm[t + off];
    __syncthreads();
  }
  if (t == 0) partials[blockIdx.x] = sm[0];
}

// single-launch scan: per-block redundant top scan of partials (nb <= 256),
// then the block's own 512-element chunk scan.
__global__ __launch_bounds__(256) void scan_all(
    const int* __restrict__ deg, const int* __restrict__ partials,
    int* __restrict__ rowptr, int nb, int n) {
  __shared__ int ps[256];
  __shared__ int wsum[4];
  int t = threadIdx.x;
  int pv = (t < nb) ? partials[t] : 0;
  ps[t] = pv;
  __syncthreads();
  for (int off = 1; off < 256; off <<= 1) {
    int u = (t >= off) ? ps[t - off] : 0;
    __syncthreads();
    ps[t] += u;
    __syncthreads();
  }
  const int b = blockIdx.x;
  int myoff = ps[b] - partials[b];   // exclusive offset of this block's chunk
  int total = ps[nb - 1];

  int base = b * SCHUNK;
  int lane = t & 63, wave = t >> 6;
  int i0 = base + 2 * t, i1 = i0 + 1;
  int d0 = (i0 < n) ? deg[i0] : 0;
  int d1 = (i1 < n) ? deg[i1] : 0;
  int s = d0 + d1;
  int incl = s;
#pragma unroll
  for (int off = 1; off < 64; off <<= 1) {
    int u = __shfl_up(incl, off);
    if (lane >= off) incl += u;
  }
  if (lane == 63) wsum[wave] = incl;
  __syncthreads();
  int woff = 0;
  for (int w = 0; w < wave; ++w) woff += wsum[w];
  int excl = woff + (incl - s) + myoff;
  if (i0 < n) rowptr[i0] = excl;
  if (i1 < n) rowptr[i1] = excl + d0;
  if (b == nb - 1 && t == 0) rowptr[n] = total;
}

// atomic-free scatter, packed 4B record {dst:u16 | val:bf16}.
__global__ void scatter_kernel(const int* __restrict__ src, const int* __restrict__ dst,
                               const float* __restrict__ val, const int* __restrict__ rank,
                               const int* __restrict__ rowptr,
                               unsigned int* __restrict__ csr, int e) {
  int i = blockIdx.x * blockDim.x + threadIdx.x;
  int e2 = e >> 1;
  if (i < e2) {
    int2 s2 = ((const int2*)src)[i];
    int2 d2 = ((const int2*)dst)[i];
    float2 v2 = ((const float2*)val)[i];
    int2 r2 = ((const int2*)rank)[i];
    unsigned int p0 = ((unsigned int)d2.x & 0xFFFFu) | ((unsigned int)f2bf(v2.x) << 16);
    unsigned int p1 = ((unsigned int)d2.y & 0xFFFFu) | ((unsigned int)f2bf(v2.y) << 16);
    csr[rowptr[s2.x] + r2.x] = p0;
    csr[rowptr[s2.y] + r2.y] = p1;
  } else if (i == e2 && (e & 1)) {
    int j = e - 1;
    csr[rowptr[src[j]] + rank[j]] =
        ((unsigned int)dst[j] & 0xFFFFu) | ((unsigned int)f2bf(val[j]) << 16);
  }
}

// ---------------- per-node attention: lane = (edge-slot, head) -------------
// one wave per node (r13-proven; compiler handles load/consume overlap).
// Delivered BW 413MB/63.5us = 6.5 TB/s ~= achievable ceiling -> at roofline.
__global__ __launch_bounds__(256) void node_kernel(
    const unsigned short* __restrict__ qb, const unsigned short* __restrict__ kvb,
    const int* __restrict__ rowptr, const unsigned int* __restrict__ csr,
    float* __restrict__ out, int n) {
  int wid = (blockIdx.x * blockDim.x + threadIdx.x) >> 6;
  int lane = threadIdx.x & 63;
  if (wid >= n) return;
  const int head = lane & 7;
  const int eg = lane >> 3;

  // q[head][0..15] -> 16 f32 (scaled already)
  const uint4* qr = (const uint4*)(qb + (size_t)wid * HID + head * 16);
  uint4 q0 = qr[0], q1 = qr[1];
  float qf[16];
  {
    unsigned int qd[8] = {q0.x, q0.y, q0.z, q0.w, q1.x, q1.y, q1.z, q1.w};
#pragma unroll
    for (int j = 0; j < 8; ++j) { qf[2 * j] = blo(qd[j]); qf[2 * j + 1] = bhi(qd[j]); }
  }

  int beg = rowptr[wid], end = rowptr[wid + 1];
  float m = -INFINITY, s = 0.f;
  float o[16];
#pragma unroll
  for (int j = 0; j < 16; ++j) o[j] = 0.f;

  for (int base = beg; base < end; base += 8) {
    int i = base + eg;
    bool valid = i < end;
    unsigned int rec = valid ? csr[i] : 0u;
    int d = rec & 0xFFFFu;
    if (d > n - 1) d = n - 1;          // defensive clamp (no OOB gather)
    float vale = bhi(rec);             // val as bf16 in high half

    const uint4* kr = (const uint4*)(kvb + (size_t)d * (2 * HID) + head * 16);
    uint4 ka = kr[0], kb2 = kr[1];     // k dims 0..15
    uint4 va = kr[16], vb2 = kr[17];   // v dims 0..15 (+128 shorts)

    float dot = 0.f;
    {
      unsigned int kd[8] = {ka.x, ka.y, ka.z, ka.w, kb2.x, kb2.y, kb2.z, kb2.w};
#pragma unroll
      for (int j = 0; j < 8; ++j)
        dot += qf[2 * j] * blo(kd[j]) + qf[2 * j + 1] * bhi(kd[j]);
    }
    float score = valid ? dot * vale : -INFINITY;

    // chunk max across the 8 edge slots (same head)
    float mx = score;
    mx = fmaxf(mx, __shfl_xor(mx, 8));
    mx = fmaxf(mx, __shfl_xor(mx, 16));
    mx = fmaxf(mx, __shfl_xor(mx, 32));

    if (!__all(mx <= m + 8.f)) {       // rare: rescale (wave-uniform branch)
      float mn = fmaxf(m, mx);
      float c = __expf(m - mn);        // first chunk: exp(-inf)=0 zeroes s,o
      s *= c;
#pragma unroll
      for (int j = 0; j < 16; ++j) o[j] *= c;
      m = mn;
    }

    float w = __expf(score - m);       // invalid: exp(-inf)=0
    s += w;
    {
      unsigned int vd[8] = {va.x, va.y, va.z, va.w, vb2.x, vb2.y, vb2.z, vb2.w};
#pragma unroll
      for (int j = 0; j < 8; ++j) {
        o[2 * j]     += w * blo(vd[j]);
        o[2 * j + 1] += w * bhi(vd[j]);
      }
    }
  }

  // merge the 8 edge-slot partials (m already common per head)
  s += __shfl_xor(s, 8); s += __shfl_xor(s, 16); s += __shfl_xor(s, 32);
#pragma unroll
  for (int j = 0; j < 16; ++j) {
    o[j] += __shfl_xor(o[j], 8);
    o[j] += __shfl_xor(o[j], 16);
    o[j] += __shfl_xor(o[j], 32);
  }

  float inv = (s > 0.f) ? 1.f / s : 0.f;
#pragma unroll
  for (int dd = 0; dd < 16; ++dd) {
    if (eg == (dd & 7))
      out[(size_t)wid * HID + dd * 8 + head] = o[dd] * inv;
  }
}

// ---------------- launcher ----------------
static inline size_t align16(size_t x) { return (x + 15) & ~(size_t)15; }

extern "C" void kernel_launch(void* const* d_in, const int* in_sizes, int n_in,
                              void* d_out, int out_size, void* d_ws, size_t ws_size,
                              hipStream_t stream) {
  const float* h  = (const float*)d_in[0];
  const float* val = (const float*)d_in[1];
  const float* Wq = (const float*)d_in[2];
  const float* bq = (const float*)d_in[3];
  const float* Wk = (const float*)d_in[4];
  const float* bk = (const float*)d_in[5];
  const float* Wv = (const float*)d_in[6];
  const float* bv = (const float*)d_in[7];
  const int* src  = (const int*)d_in[8];
  const int* dst  = (const int*)d_in[9];

  int N = in_sizes[0] / HID;
  int E = in_sizes[8];
  float* out = (float*)d_out;
  int nb = (N + SCHUNK - 1) / SCHUNK;   // must be <= 256 (N <= 131072)

  // workspace layout — every section 16B-aligned (vector loads require it)
  size_t base = (size_t)d_ws;
  size_t off = 0;
  unsigned short* qb  = (unsigned short*)(base + off);  off = align16(off + (size_t)N * HID * 2);
  unsigned short* kvb = (unsigned short*)(base + off);  off = align16(off + (size_t)2 * N * HID * 2);
  int* rowptr  = (int*)(base + off);                    off = align16(off + (size_t)(N + 1) * 4);
  int* deg     = (int*)(base + off);                    off = align16(off + (size_t)N * 4);
  int* partials = (int*)(base + off);                   off = align16(off + (size_t)nb * 4);
  int* rank    = (int*)(base + off);                    off = align16(off + (size_t)E * 4);
  unsigned int* csr = (unsigned int*)(base + off);      off = align16(off + (size_t)E * 4);

  hipMemsetAsync(deg, 0, sizeof(int) * (size_t)N, stream);

  int bp = (N + 63) / 64;
  int he = (E + 255) / 256;
  proj_hist<<<3 * bp + he, 256, 0, stream>>>(
      h, Wq, Wk, Wv, bq, bk, bv, qb, kvb, src, deg, rank, N, bp, he, E);

  reduce_blocks<<<nb, 256, 0, stream>>>(deg, partials, N);
  scan_all<<<nb, 256, 0, stream>>>(deg, partials, rowptr, nb, N);
  scatter_kernel<<<((E / 2) + 256) / 256, 256, 0, stream>>>(
      src, dst, val, rank, rowptr, csr, E);

  node_kernel<<<(N + 3) / 4, 256, 0, stream>>>(qb, kvb, rowptr, csr, out, N);
}

// Round 21
// 147.364 us; speedup vs baseline: 1.2420x; 1.2420x over previous
//
#include <hip/hip_runtime.h>
#include <hip/hip_bf16.h>
#include <math.h>

#define HID 128
#define NH  8
#define SCHUNK 512  // elements per scan block
#define TPAD 136    // 128 + 8 shorts: 272B row stride (16B-aligned, bank-shifted)

typedef __attribute__((ext_vector_type(8))) short short8;
typedef __attribute__((ext_vector_type(4))) float f32x4;

static __device__ __forceinline__ float blo(unsigned int u) {
  union { unsigned int i; float f; } c; c.i = u << 16; return c.f;
}
static __device__ __forceinline__ float bhi(unsigned int u) {
  union { unsigned int i; float f; } c; c.i = u & 0xFFFF0000u; return c.f;
}
static __device__ __forceinline__ unsigned short f2bf(float f) {
  union { float f; unsigned int i; } c; c.f = f;
  unsigned int r = c.i + 0x7FFFu + ((c.i >> 16) & 1u);  // round-nearest-even
  return (unsigned short)(r >> 16);
}

// load 8 consecutive fp32 and convert to a bf16 MFMA fragment in-register
static __device__ __forceinline__ short8 ldconv8(const float* __restrict__ p) {
  float4 x = *(const float4*)p;
  float4 y = *(const float4*)(p + 4);
  short8 r;
  r[0] = (short)f2bf(x.x); r[1] = (short)f2bf(x.y);
  r[2] = (short)f2bf(x.z); r[3] = (short)f2bf(x.w);
  r[4] = (short)f2bf(y.x); r[5] = (short)f2bf(y.y);
  r[6] = (short)f2bf(y.z); r[7] = (short)f2bf(y.w);
  return r;
}

// convert 3 weight matrices + zero deg in one launch (blockIdx.y picks role)
__global__ void convert3_kernel(const float* __restrict__ s0, const float* __restrict__ s1,
                                const float* __restrict__ s2,
                                unsigned short* __restrict__ dst, int n8,
                                int* __restrict__ deg, int n) {
  if (blockIdx.y == 3) {  // deg-zero role
    for (int i = blockIdx.x * blockDim.x + threadIdx.x; i < n;
         i += gridDim.x * blockDim.x)
      deg[i] = 0;
    return;
  }
  const float* s = (blockIdx.y == 0) ? s0 : (blockIdx.y == 1) ? s1 : s2;
  unsigned short* d = dst + (size_t)blockIdx.y * n8 * 8;
  for (int i = blockIdx.x * blockDim.x + threadIdx.x; i < n8;
       i += gridDim.x * blockDim.x) {
    float4 a = ((const float4*)s)[2 * i];
    float4 b = ((const float4*)s)[2 * i + 1];
    uint4 o;
    o.x = ((unsigned int)f2bf(a.y) << 16) | f2bf(a.x);
    o.y = ((unsigned int)f2bf(a.w) << 16) | f2bf(a.z);
    o.z = ((unsigned int)f2bf(b.y) << 16) | f2bf(b.x);
    o.w = ((unsigned int)f2bf(b.w) << 16) | f2bf(b.z);
    ((uint4*)d)[i] = o;
  }
}

// ---------------- fused MFMA projection | histogram+rank (INTERLEAVED) -----
// Roles interleaved via Bresenham so proj and hist blocks are co-resident on
// every CU: hist waves park on atomic returns while proj waves use the
// MFMA/LDS pipes. W pre-converted to bf16 (keeps proj at 48 VGPR — r20's
// in-reg W conversion cost 72 VGPR -> occupancy 26% -> throttled hist).
__global__ __launch_bounds__(256) void proj_hist(
    const float* __restrict__ h, const unsigned short* __restrict__ wb,
    const float* __restrict__ bq, const float* __restrict__ bk,
    const float* __restrict__ bv,
    unsigned short* __restrict__ qb, unsigned short* __restrict__ kvb,
    const int* __restrict__ src, int* __restrict__ deg, int* __restrict__ rank,
    int n, int bp, int nhist, int e) {
  __shared__ unsigned short tile[4][16][TPAD];  // per-wave 16x128 (+pad)

  const int P = 3 * bp;
  const int T = P + nhist;
  const long long a = (long long)blockIdx.x * P;
  const int d = (int)(a / T);
  const int c = (int)((a + P) / T);

  if (c == d) {
    // ---- histogram + rank role (hist_id = bx - c) ----
    int i = (blockIdx.x - c) * 256 + threadIdx.x;
    if (i < e) rank[i] = atomicAdd(&deg[src[i]], 1);
    return;
  }

  // ---- projection role (proj_id = d, each value in [0,P) exactly once) ----
  const int y = d / bp;
  const int bxx = d - y * bp;
  const unsigned short* W = wb + (size_t)y * HID * HID;
  const float* bias = (y == 0) ? bq : (y == 1) ? bk : bv;
  const float scale = (y == 0) ? 0.25f : 1.0f;  // q: DH^-0.5

  unsigned short* out;
  int ostride;
  if (y == 0)      { out = qb;        ostride = HID; }
  else if (y == 1) { out = kvb;       ostride = 2 * HID; }
  else             { out = kvb + HID; ostride = 2 * HID; }

  const int lane = threadIdx.x & 63;
  const int wave = threadIdx.x >> 6;
  const int n0 = bxx * 64 + wave * 16;

  int arow = n0 + (lane & 15);
  if (arow > n - 1) arow = n - 1;
  const int koff = (lane >> 4) * 8;

  const float* hr = h + (size_t)arow * HID + koff;
  short8 a0 = ldconv8(hr +  0);
  short8 a1 = ldconv8(hr + 32);
  short8 a2 = ldconv8(hr + 64);
  short8 a3 = ldconv8(hr + 96);

#pragma unroll
  for (int ct = 0; ct < 8; ++ct) {
    const int cc = ct * 16 + (lane & 15);
    const unsigned short* wr = W + (size_t)cc * HID + koff;
    f32x4 acc = {0.f, 0.f, 0.f, 0.f};
    acc = __builtin_amdgcn_mfma_f32_16x16x32_bf16(a0, *(const short8*)(wr +  0), acc, 0, 0, 0);
    acc = __builtin_amdgcn_mfma_f32_16x16x32_bf16(a1, *(const short8*)(wr + 32), acc, 0, 0, 0);
    acc = __builtin_amdgcn_mfma_f32_16x16x32_bf16(a2, *(const short8*)(wr + 64), acc, 0, 0, 0);
    acc = __builtin_amdgcn_mfma_f32_16x16x32_bf16(a3, *(const short8*)(wr + 96), acc, 0, 0, 0);

    const float bb = bias[cc];
    const int cp = (cc & 7) * 16 + (cc >> 3);  // head-major position within row
#pragma unroll
    for (int r = 0; r < 4; ++r) {
      int rl = (lane >> 4) * 4 + r;            // local row 0..15
      tile[wave][rl][cp] = f2bf((acc[r] + bb) * scale);
    }
  }

  // coalesced write-out: 16 rows x 256B, 16 lanes cover one row per pass
#pragma unroll
  for (int p = 0; p < 4; ++p) {
    int rl = p * 4 + (lane >> 4);
    int row = n0 + rl;
    if (row < n) {
      uint4 vv = *(const uint4*)&tile[wave][rl][(lane & 15) * 8];
      *(uint4*)(out + (size_t)row * ostride + (lane & 15) * 8) = vv;
    }
  }
}

__global__ __launch_bounds__(256) void reduce_blocks(
    const int* __restrict__ deg, int* __restrict__ partials, int n) {
  __shared__ int sm[256];
  int base = blockIdx.x * SCHUNK;
  int t = threadIdx.x;
  int i0 = base + t, i1 = base + t + 256;
  int s = ((i0 < n) ? deg[i0] : 0) + ((i1 < n) ? deg[i1] : 0);
  sm[t] = s;
  __syncthreads();
  for (int off = 128; off > 0; off >>= 1) {
    if (t < off) sm[t] += sm[t + off];
    __syncthreads();
  }
  if (t == 0) partials[blockIdx.x] = sm[0];
}

// single-launch scan: per-block redundant top scan of partials (nb <= 256),
// then the block's own 512-element chunk scan.
__global__ __launch_bounds__(256) void scan_all(
    const int* __restrict__ deg, const int* __restrict__ partials,
    int* __restrict__ rowptr, int nb, int n) {
  __shared__ int ps[256];
  __shared__ int wsum[4];
  int t = threadIdx.x;
  int pv = (t < nb) ? partials[t] : 0;
  ps[t] = pv;
  __syncthreads();
  for (int off = 1; off < 256; off <<= 1) {
    int u = (t >= off) ? ps[t - off] : 0;
    __syncthreads();
    ps[t] += u;
    __syncthreads();
  }
  const int b = blockIdx.x;
  int myoff = ps[b] - partials[b];   // exclusive offset of this block's chunk
  int total = ps[nb - 1];

  int base = b * SCHUNK;
  int lane = t & 63, wave = t >> 6;
  int i0 = base + 2 * t, i1 = i0 + 1;
  int d0 = (i0 < n) ? deg[i0] : 0;
  int d1 = (i1 < n) ? deg[i1] : 0;
  int s = d0 + d1;
  int incl = s;
#pragma unroll
  for (int off = 1; off < 64; off <<= 1) {
    int u = __shfl_up(incl, off);
    if (lane >= off) incl += u;
  }
  if (lane == 63) wsum[wave] = incl;
  __syncthreads();
  int woff = 0;
  for (int w = 0; w < wave; ++w) woff += wsum[w];
  int excl = woff + (incl - s) + myoff;
  if (i0 < n) rowptr[i0] = excl;
  if (i1 < n) rowptr[i1] = excl + d0;
  if (b == nb - 1 && t == 0) rowptr[n] = total;
}

// atomic-free scatter, packed 4B record {dst:u16 | val:bf16}.
__global__ void scatter_kernel(const int* __restrict__ src, const int* __restrict__ dst,
                               const float* __restrict__ val, const int* __restrict__ rank,
                               const int* __restrict__ rowptr,
                               unsigned int* __restrict__ csr, int e) {
  int i = blockIdx.x * blockDim.x + threadIdx.x;
  int e2 = e >> 1;
  if (i < e2) {
    int2 s2 = ((const int2*)src)[i];
    int2 d2 = ((const int2*)dst)[i];
    float2 v2 = ((const float2*)val)[i];
    int2 r2 = ((const int2*)rank)[i];
    unsigned int p0 = ((unsigned int)d2.x & 0xFFFFu) | ((unsigned int)f2bf(v2.x) << 16);
    unsigned int p1 = ((unsigned int)d2.y & 0xFFFFu) | ((unsigned int)f2bf(v2.y) << 16);
    csr[rowptr[s2.x] + r2.x] = p0;
    csr[rowptr[s2.y] + r2.y] = p1;
  } else if (i == e2 && (e & 1)) {
    int j = e - 1;
    csr[rowptr[src[j]] + rank[j]] =
        ((unsigned int)dst[j] & 0xFFFFu) | ((unsigned int)f2bf(val[j]) << 16);
  }
}

// ---------------- per-node attention: lane = (edge-slot, head) -------------
// one wave per node (r13-proven; compiler handles load/consume overlap).
// Delivered BW 413MB/63.5us = 6.5 TB/s ~= achievable ceiling -> at roofline.
__global__ __launch_bounds__(256) void node_kernel(
    const unsigned short* __restrict__ qb, const unsigned short* __restrict__ kvb,
    const int* __restrict__ rowptr, const unsigned int* __restrict__ csr,
    float* __restrict__ out, int n) {
  int wid = (blockIdx.x * blockDim.x + threadIdx.x) >> 6;
  int lane = threadIdx.x & 63;
  if (wid >= n) return;
  const int head = lane & 7;
  const int eg = lane >> 3;

  // q[head][0..15] -> 16 f32 (scaled already)
  const uint4* qr = (const uint4*)(qb + (size_t)wid * HID + head * 16);
  uint4 q0 = qr[0], q1 = qr[1];
  float qf[16];
  {
    unsigned int qd[8] = {q0.x, q0.y, q0.z, q0.w, q1.x, q1.y, q1.z, q1.w};
#pragma unroll
    for (int j = 0; j < 8; ++j) { qf[2 * j] = blo(qd[j]); qf[2 * j + 1] = bhi(qd[j]); }
  }

  int beg = rowptr[wid], end = rowptr[wid + 1];
  float m = -INFINITY, s = 0.f;
  float o[16];
#pragma unroll
  for (int j = 0; j < 16; ++j) o[j] = 0.f;

  for (int base = beg; base < end; base += 8) {
    int i = base + eg;
    bool valid = i < end;
    unsigned int rec = valid ? csr[i] : 0u;
    int d = rec & 0xFFFFu;
    if (d > n - 1) d = n - 1;          // defensive clamp (no OOB gather)
    float vale = bhi(rec);             // val as bf16 in high half

    const uint4* kr = (const uint4*)(kvb + (size_t)d * (2 * HID) + head * 16);
    uint4 ka = kr[0], kb2 = kr[1];     // k dims 0..15
    uint4 va = kr[16], vb2 = kr[17];   // v dims 0..15 (+128 shorts)

    float dot = 0.f;
    {
      unsigned int kd[8] = {ka.x, ka.y, ka.z, ka.w, kb2.x, kb2.y, kb2.z, kb2.w};
#pragma unroll
      for (int j = 0; j < 8; ++j)
        dot += qf[2 * j] * blo(kd[j]) + qf[2 * j + 1] * bhi(kd[j]);
    }
    float score = valid ? dot * vale : -INFINITY;

    // chunk max across the 8 edge slots (same head)
    float mx = score;
    mx = fmaxf(mx, __shfl_xor(mx, 8));
    mx = fmaxf(mx, __shfl_xor(mx, 16));
    mx = fmaxf(mx, __shfl_xor(mx, 32));

    if (!__all(mx <= m + 8.f)) {       // rare: rescale (wave-uniform branch)
      float mn = fmaxf(m, mx);
      float c = __expf(m - mn);        // first chunk: exp(-inf)=0 zeroes s,o
      s *= c;
#pragma unroll
      for (int j = 0; j < 16; ++j) o[j] *= c;
      m = mn;
    }

    float w = __expf(score - m);       // invalid: exp(-inf)=0
    s += w;
    {
      unsigned int vd[8] = {va.x, va.y, va.z, va.w, vb2.x, vb2.y, vb2.z, vb2.w};
#pragma unroll
      for (int j = 0; j < 8; ++j) {
        o[2 * j]     += w * blo(vd[j]);
        o[2 * j + 1] += w * bhi(vd[j]);
      }
    }
  }

  // merge the 8 edge-slot partials (m already common per head)
  s += __shfl_xor(s, 8); s += __shfl_xor(s, 16); s += __shfl_xor(s, 32);
#pragma unroll
  for (int j = 0; j < 16; ++j) {
    o[j] += __shfl_xor(o[j], 8);
    o[j] += __shfl_xor(o[j], 16);
    o[j] += __shfl_xor(o[j], 32);
  }

  float inv = (s > 0.f) ? 1.f / s : 0.f;
#pragma unroll
  for (int dd = 0; dd < 16; ++dd) {
    if (eg == (dd & 7))
      out[(size_t)wid * HID + dd * 8 + head] = o[dd] * inv;
  }
}

// ---------------- launcher ----------------
static inline size_t align16(size_t x) { return (x + 15) & ~(size_t)15; }

extern "C" void kernel_launch(void* const* d_in, const int* in_sizes, int n_in,
                              void* d_out, int out_size, void* d_ws, size_t ws_size,
                              hipStream_t stream) {
  const float* h  = (const float*)d_in[0];
  const float* val = (const float*)d_in[1];
  const float* Wq = (const float*)d_in[2];
  const float* bq = (const float*)d_in[3];
  const float* Wk = (const float*)d_in[4];
  const float* bk = (const float*)d_in[5];
  const float* Wv = (const float*)d_in[6];
  const float* bv = (const float*)d_in[7];
  const int* src  = (const int*)d_in[8];
  const int* dst  = (const int*)d_in[9];

  int N = in_sizes[0] / HID;
  int E = in_sizes[8];
  float* out = (float*)d_out;
  int nb = (N + SCHUNK - 1) / SCHUNK;   // must be <= 256 (N <= 131072)

  // workspace layout — every section 16B-aligned (vector loads require it)
  size_t base = (size_t)d_ws;
  size_t off = 0;
  unsigned short* wb  = (unsigned short*)(base + off);  off = align16(off + (size_t)3 * HID * HID * 2);
  unsigned short* qb  = (unsigned short*)(base + off);  off = align16(off + (size_t)N * HID * 2);
  unsigned short* kvb = (unsigned short*)(base + off);  off = align16(off + (size_t)2 * N * HID * 2);
  int* rowptr  = (int*)(base + off);                    off = align16(off + (size_t)(N + 1) * 4);
  int* deg     = (int*)(base + off);                    off = align16(off + (size_t)N * 4);
  int* partials = (int*)(base + off);                   off = align16(off + (size_t)nb * 4);
  int* rank    = (int*)(base + off);                    off = align16(off + (size_t)E * 4);
  unsigned int* csr = (unsigned int*)(base + off);      off = align16(off + (size_t)E * 4);

  int n8_w = HID * HID / 8;
  convert3_kernel<<<dim3(128, 4), 256, 0, stream>>>(
      Wq, Wk, Wv, wb, n8_w, deg, N);

  int bp = (N + 63) / 64;
  int he = (E + 255) / 256;
  proj_hist<<<3 * bp + he, 256, 0, stream>>>(
      h, wb, bq, bk, bv, qb, kvb, src, deg, rank, N, bp, he, E);

  reduce_blocks<<<nb, 256, 0, stream>>>(deg, partials, N);
  scan_all<<<nb, 256, 0, stream>>>(deg, partials, rowptr, nb, N);
  scatter_kernel<<<((E / 2) + 256) / 256, 256, 0, stream>>>(
      src, dst, val, rank, rowptr, csr, E);

  node_kernel<<<(N + 3) / 4, 256, 0, stream>>>(qb, kvb, rowptr, csr, out, N);
}